// Round 8
// baseline (371.726 us; speedup 1.0000x reference)
//
#include <hip/hip_runtime.h>
#include <stdint.h>

// FullyConnectedSteerableGeometricProductLayer (G(3,0), 8 blades)
// B=2048, N_IN=N_OUT=512, N_PATHS=20. ALL I/O IS FLOAT32; internal bf16 MFMA.
//
// R12 = R11 + gemm2 2-way K-split (occupancy lever).
// Evidence R6-R11: time flat at ~180us across FETCH 167-230MB, WRITE 37-262MB,
// conflicts 0-2.4e7, fences/no-fences -> not traffic- or conflict-bound.
// MfmaUtil 18 / VALUBusy 29 / Occ 22% -> half the cycles are waits; grid 512
// = 2 barrier-coupled blocks/CU is too thin to hide staging latency. R6 (16
// waves/CU) was the only sub-175us point. K-split: seg0 (k<2304) -> out
// (+bias), seg1 -> pp partial buffer (f32, +33.5MB ws); addred folds. 1024
// independent blocks = 4/CU = 16 waves/CU. XCD = bm%8 keeps all writers of
// an out-line co-XCD (R11 write-merge preserved).

#define B_DIM 2048
#define N_DIM 512
#define PLANE (B_DIM * N_DIM)   // 1048576
#define WPLANE (N_DIM * N_DIM)  // 262144
#define KTOT (9 * N_DIM)        // 4608

using frag8 = __attribute__((ext_vector_type(8))) short;  // 8 bf16
using f32x4 = __attribute__((ext_vector_type(4))) float;  // MFMA acc

__device__ __forceinline__ float bf2f(unsigned short u) {
  union { unsigned int i; float f; } v;
  v.i = ((unsigned int)u) << 16;
  return v.f;
}
__device__ __forceinline__ unsigned short f2bf(float f) {  // RNE
  unsigned int u = __float_as_uint(f);
  return (unsigned short)((u + 0x7FFFu + ((u >> 16) & 1u)) >> 16);
}
// two bf16 pairs (dwords a,r) -> packed bf16 products (round-half-up)
__device__ __forceinline__ unsigned int pairpack(unsigned int a, unsigned int r) {
  const float pe = __uint_as_float(a << 16) * __uint_as_float(r << 16);
  const float po = __uint_as_float(a & 0xFFFF0000u) * __uint_as_float(r & 0xFFFF0000u);
  return __builtin_amdgcn_perm(__float_as_uint(po) + 0x8000u,
                               __float_as_uint(pe) + 0x8000u, 0x07060302u);
}

typedef const unsigned int __attribute__((address_space(1)))* gas_t;
typedef unsigned int __attribute__((address_space(3)))* las_t;
// async 16B/lane global->LDS; LDS dest = wave-uniform base + lane*16
__device__ __forceinline__ void gload16(const void* g, void* l) {
  __builtin_amdgcn_global_load_lds((gas_t)g, (las_t)l, 16, 0, 0);
}

// ---- Cayley tables (verified end-to-end R3/R4/R5): sgn(j,k), p(j,k), grade.
// i(j,k) = P(P(j)^P(k)) with P = swap(3,4) involution (R4/R5-verified).
#define SGN_INIT {                                                     \
  {0,0,0,0,0x8000,0x8000,0x8000,0x8000},                               \
  {0,0,0,0,0x8000,0x8000,0x8000,0x8000},                               \
  {0,0x8000,0,0,0,0,0x8000,0},                                         \
  {0,0x8000,0x8000,0,0x8000,0,0,0x8000},                               \
  {0,0x8000,0,0,0,0,0x8000,0},                                         \
  {0,0x8000,0x8000,0,0x8000,0,0,0x8000},                               \
  {0,0,0x8000,0,0,0x8000,0,0},                                         \
  {0,0,0x8000,0,0,0x8000,0,0} }
#define PJK_INIT {                                                     \
  {0,4,4,4,10,10,10,16},  {5,1,11,11,6,6,17,12},                       \
  {5,11,1,11,6,17,6,12},  {5,11,11,1,17,6,6,12},                       \
  {13,7,7,18,2,14,14,8},  {13,7,18,7,14,2,14,8},                       \
  {13,18,7,7,14,14,2,8},  {19,15,15,15,9,9,9,3} }
#define GR_INIT {0,1,1,1,2,2,2,3}

// ---------------- repack / prebuild (f32 in -> bf16 planes) ----------------

__global__ __launch_bounds__(256) void repack_x(const float* __restrict__ x,
                                                unsigned short* __restrict__ xt) {
  const int t = blockIdx.x * 256 + threadIdx.x;
  const float4 v0 = *(const float4*)(x + (size_t)t * 8);
  const float4 v1 = *(const float4*)(x + (size_t)t * 8 + 4);
  const float v[8] = {v0.x, v0.y, v0.z, v0.w, v1.x, v1.y, v1.z, v1.w};
#pragma unroll
  for (int i = 0; i < 8; ++i) xt[(size_t)i * PLANE + t] = f2bf(v[i]);
}

__global__ __launch_bounds__(256) void repack_wr(const float* __restrict__ wr,
                                                 unsigned short* __restrict__ wrt) {
  const int t = blockIdx.x * 256 + threadIdx.x;
  const float4 v = *(const float4*)(wr + (size_t)t * 4);
  const float p[4] = {v.x, v.y, v.z, v.w};
#pragma unroll
  for (int g = 0; g < 4; ++g) wrt[(size_t)g * WPLANE + t] = f2bf(p[g]);
}

__global__ __launch_bounds__(256) void build_W(const float* __restrict__ w,
                                               const float* __restrict__ wl,
                                               unsigned short* __restrict__ Wall) {
  constexpr int PJK[8][8] = PJK_INIT;
  constexpr unsigned short SGN[8][8] = SGN_INIT;
  constexpr int GR[8] = GR_INIT;
  const int t = blockIdx.x * 256 + threadIdx.x;
  const int m = t >> 9, n = t & 511;
  const float* wrow = w + (size_t)t * 20;
  const float* wlrow = wl + (size_t)t * 4;
  unsigned short w20[20];
#pragma unroll
  for (int p = 0; p < 20; ++p) w20[p] = f2bf(wrow[p]);
  unsigned short wl4[4];
#pragma unroll
  for (int g = 0; g < 4; ++g) wl4[g] = f2bf(wlrow[g]);
#pragma unroll
  for (int j = 0; j < 8; ++j) {
    const size_t base = ((size_t)j * N_DIM + m) * KTOT + n;
#pragma unroll
    for (int k = 0; k < 8; ++k)
      Wall[base + (size_t)k * N_DIM] = (unsigned short)(w20[PJK[j][k]] ^ SGN[j][k]);
    Wall[base + (size_t)8 * N_DIM] = wl4[GR[j]];
  }
}

__global__ __launch_bounds__(256) void normk(unsigned short* __restrict__ xre,
                                             const float* __restrict__ na) {
  const int t = blockIdx.x * 256 + threadIdx.x;
  const int n = t & 511;
  float v[8];
#pragma unroll
  for (int p = 0; p < 8; ++p) v[p] = bf2f(xre[(size_t)p * PLANE + t]);
  const float n0 = fabsf(v[0]);
  const float n1 = sqrtf(v[1] * v[1] + v[2] * v[2] + v[3] * v[3]);
  const float n2 = sqrtf(v[4] * v[4] + v[5] * v[5] + v[6] * v[6]);
  const float n3 = fabsf(v[7]);
  float f[4];
  const float nm[4] = {n0, n1, n2, n3};
#pragma unroll
  for (int g = 0; g < 4; ++g) {
    const float a = na[n * 4 + g];
    const float sig = 1.0f / (1.0f + __expf(-a));
    f[g] = sig * (nm[g] - 1.0f) + 1.0f + 1e-6f;
  }
  v[0] /= f[0];
  v[1] /= f[1]; v[2] /= f[1]; v[3] /= f[1];
  v[4] /= f[2]; v[5] /= f[2]; v[6] /= f[2];
  v[7] /= f[3];
#pragma unroll
  for (int p = 0; p < 8; ++p) xre[(size_t)p * PLANE + t] = f2bf(v[p]);
  xre[(size_t)8 * PLANE + t] = 0x3F80;  // 1.0 plane -> 'left' term in gemm2
}

// ------- gemm1: xre[z] = xt[z] * wrt[g(z)]^T  (128x128, 4 waves) -----------

__global__ __launch_bounds__(256, 3) void gemm1(const unsigned short* __restrict__ xt,
                                                const unsigned short* __restrict__ wrt,
                                                unsigned short* __restrict__ xre) {
  constexpr int GR[8] = GR_INIT;
  __shared__ __attribute__((aligned(16))) unsigned short sA[2][4096];
  __shared__ __attribute__((aligned(16))) unsigned short sB[2][4096];
  const int bm0 = blockIdx.x * 128, bn0 = blockIdx.y * 128, z = blockIdx.z;
  const unsigned short* A = xt + (size_t)z * PLANE;
  const unsigned short* Bm = wrt + (size_t)GR[z] * WPLANE;
  unsigned short* C = xre + (size_t)z * PLANE;

  const int tid = (int)threadIdx.x;
  const int l = tid & 63, w = tid >> 6;
  const int wm = (w >> 1) * 64, wn = (w & 1) * 64;
  const int fr = l & 15, quad = l >> 4, msw = (fr >> 1) & 3;
  const int rdA = (wm + fr) * 32 + (quad ^ msw) * 8;
  const int rdB = (wn + fr) * 32 + (quad ^ msw) * 8;
  const int ks = (((l & 3) ^ ((l >> 3) & 3))) * 8;
  const int r0 = w * 32 + (l >> 2);
  const unsigned short* pa0 = A + (size_t)(bm0 + r0) * N_DIM + ks;
  const unsigned short* pa1 = pa0 + (size_t)16 * N_DIM;
  const unsigned short* pb0 = Bm + (size_t)(bn0 + r0) * N_DIM + ks;
  const unsigned short* pb1 = pb0 + (size_t)16 * N_DIM;
  const int db = w * 1024;  // wave LDS dest base (ushorts); op1 = +512

  f32x4 acc[4][4];
#pragma unroll
  for (int mt = 0; mt < 4; ++mt)
#pragma unroll
    for (int nt = 0; nt < 4; ++nt) acc[mt][nt] = (f32x4){0.f, 0.f, 0.f, 0.f};

  gload16(pa0, &sA[0][db]);
  gload16(pa1, &sA[0][db + 512]);
  gload16(pb0, &sB[0][db]);
  gload16(pb1, &sB[0][db + 512]);
  __syncthreads();

#pragma unroll 2
  for (int it = 0; it < 16; ++it) {
    const int cur = it & 1;
    if (it < 15) {
      const int off = (it + 1) * 32;
      gload16(pa0 + off, &sA[cur ^ 1][db]);
      gload16(pa1 + off, &sA[cur ^ 1][db + 512]);
      gload16(pb0 + off, &sB[cur ^ 1][db]);
      gload16(pb1 + off, &sB[cur ^ 1][db + 512]);
    }
    frag8 af[4], bf[4];
#pragma unroll
    for (int t = 0; t < 4; ++t) af[t] = *(const frag8*)&sA[cur][rdA + t * 512];
#pragma unroll
    for (int t = 0; t < 4; ++t) bf[t] = *(const frag8*)&sB[cur][rdB + t * 512];
#pragma unroll
    for (int mt = 0; mt < 4; ++mt)
#pragma unroll
      for (int nt = 0; nt < 4; ++nt)
        acc[mt][nt] = __builtin_amdgcn_mfma_f32_16x16x32_bf16(af[mt], bf[nt], acc[mt][nt], 0, 0, 0);
    __syncthreads();
  }
  // C/D: col = lane&15, row = quad*4 + reg
#pragma unroll
  for (int mt = 0; mt < 4; ++mt) {
    const int row0 = bm0 + wm + mt * 16 + quad * 4;
#pragma unroll
    for (int nt = 0; nt < 4; ++nt) {
      const int col = bn0 + wn + nt * 16 + fr;
#pragma unroll
      for (int r = 0; r < 4; ++r)
        C[(size_t)(row0 + r) * N_DIM + col] = f2bf(acc[mt][nt][r]);
    }
  }
}

// ------- gemm2: out = (pair * Wall_j + bias)/sqrt(2), 2-way K-split --------
// grid (16, 8, 8): by = bn(2b) | seg(bit2). seg0 K=[0,2304)->out(+bias),
// seg1 K=[2304,4608)->pp. 1024 independent blocks = 4/CU = 16 waves/CU.
// XCD = bm%8 (natural rr): all j/bn/seg of a bm co-XCD -> write lines merge.

__global__ __launch_bounds__(256, 4) void gemm2(const unsigned short* __restrict__ xt,
                                                const unsigned short* __restrict__ xre,
                                                const unsigned short* __restrict__ Wall,
                                                const float* __restrict__ bl,
                                                float* __restrict__ out,
                                                float* __restrict__ pp) {
  __shared__ __attribute__((aligned(16))) unsigned short sA[2][4096];
  __shared__ __attribute__((aligned(16))) unsigned short sB[2][4096];
  const int bm0 = blockIdx.x * 128;
  const int bn0 = ((int)blockIdx.y & 3) * 128;
  const int seg = (int)blockIdx.y >> 2;
  const int j = blockIdx.z;
  const int kc0 = seg * 72;  // first K32-chunk of this segment

  const int tid = (int)threadIdx.x;
  const int l = tid & 63, w = tid >> 6;
  const int wm = (w >> 1) * 64, wn = (w & 1) * 64;
  const int fr = l & 15, quad = l >> 4, msw = (fr >> 1) & 3;
  const int rdA = (wm + fr) * 32 + (quad ^ msw) * 8;
  const int rdB = (wn + fr) * 32 + (quad ^ msw) * 8;
  const int ks = (((l & 3) ^ ((l >> 3) & 3))) * 8;
  const int r0 = w * 32 + (l >> 2);
  const int db = w * 1024;
  const int pj = (j == 3 || j == 4) ? (j ^ 7) : j;  // P(j)

  // A sources: un-swizzled col (reg-staged); write slot swizzled.
  const size_t ar0 = (size_t)(bm0 + r0) * N_DIM + (l & 3) * 8;
  const size_t ar1 = ar0 + (size_t)16 * N_DIM;
  const int wr0 = r0 * 32 + ks, wr1 = wr0 + 512;  // (r0+16)*32+ks
  // B source: swizzled col, linear LDS dest via global_load_lds.
  const unsigned short* pw0 = Wall + ((size_t)j * N_DIM + bn0 + r0) * KTOT + ks;
  const unsigned short* pw1 = pw0 + (size_t)16 * KTOT;

  // plane index of xt for slice sl: ie = P(pj ^ P(sl)); sl=8 -> j
  auto ieof = [&](int sl) -> int {
    int ps = (sl == 3 || sl == 4) ? (sl ^ 7) : sl;
    int ix = pj ^ ps;
    ix = (ix == 3 || ix == 4) ? (ix ^ 7) : ix;
    return (sl == 8) ? j : ix;
  };

  f32x4 acc[4][4];
#pragma unroll
  for (int mt = 0; mt < 4; ++mt)
#pragma unroll
    for (int nt = 0; nt < 4; ++nt) acc[mt][nt] = (f32x4){0.f, 0.f, 0.f, 0.f};

  // ---- prologue: chunk kc0 staged (A packed+written, B gloads in flight)
  {
    const int sl0 = kc0 >> 4, n00 = (kc0 & 15) << 5;
    const unsigned short* bx = xt + (size_t)ieof(sl0) * PLANE;
    const unsigned short* be = xre + (size_t)sl0 * PLANE;
    const uint4 x0 = *(const uint4*)(bx + ar0 + n00);
    const uint4 e0 = *(const uint4*)(be + ar0 + n00);
    const uint4 x1 = *(const uint4*)(bx + ar1 + n00);
    const uint4 e1 = *(const uint4*)(be + ar1 + n00);
    gload16(pw0 + (size_t)kc0 * 32, &sB[0][db]);
    gload16(pw1 + (size_t)kc0 * 32, &sB[0][db + 512]);
    uint4 o0, o1;
    o0.x = pairpack(x0.x, e0.x); o0.y = pairpack(x0.y, e0.y);
    o0.z = pairpack(x0.z, e0.z); o0.w = pairpack(x0.w, e0.w);
    o1.x = pairpack(x1.x, e1.x); o1.y = pairpack(x1.y, e1.y);
    o1.z = pairpack(x1.z, e1.z); o1.w = pairpack(x1.w, e1.w);
    *(uint4*)&sA[0][wr0] = o0;
    *(uint4*)&sA[0][wr1] = o1;
  }
  __syncthreads();

#pragma unroll 2
  for (int it = 0; it < 72; ++it) {
    const int cur = it & 1;
    uint4 x0, e0, x1, e1;
    if (it < 71) {  // prefetch A regs + B gloads for chunk kc0+it+1
      const int kn = kc0 + it + 1;
      const int sl = kn >> 4, n0 = (kn & 15) << 5;
      int ps = (sl == 3 || sl == 4) ? (sl ^ 7) : sl;
      int ix = pj ^ ps;
      ix = (ix == 3 || ix == 4) ? (ix ^ 7) : ix;
      const int ie = (sl == 8) ? j : ix;
      const unsigned short* bx = xt + (size_t)ie * PLANE;
      const unsigned short* be = xre + (size_t)sl * PLANE;
      x0 = *(const uint4*)(bx + ar0 + n0);
      e0 = *(const uint4*)(be + ar0 + n0);
      x1 = *(const uint4*)(bx + ar1 + n0);
      e1 = *(const uint4*)(be + ar1 + n0);
      gload16(pw0 + (size_t)kn * 32, &sB[cur ^ 1][db]);
      gload16(pw1 + (size_t)kn * 32, &sB[cur ^ 1][db + 512]);
    }
    frag8 af[4], bf[4];
#pragma unroll
    for (int t = 0; t < 4; ++t) af[t] = *(const frag8*)&sA[cur][rdA + t * 512];
#pragma unroll
    for (int t = 0; t < 4; ++t) bf[t] = *(const frag8*)&sB[cur][rdB + t * 512];
#pragma unroll
    for (int mt = 0; mt < 4; ++mt)
#pragma unroll
      for (int nt = 0; nt < 4; ++nt)
        acc[mt][nt] = __builtin_amdgcn_mfma_f32_16x16x32_bf16(af[mt], bf[nt], acc[mt][nt], 0, 0, 0);
    if (it < 71) {  // pack + write A for next chunk (wait lands after MFMA)
      uint4 o0, o1;
      o0.x = pairpack(x0.x, e0.x); o0.y = pairpack(x0.y, e0.y);
      o0.z = pairpack(x0.z, e0.z); o0.w = pairpack(x0.w, e0.w);
      o1.x = pairpack(x1.x, e1.x); o1.y = pairpack(x1.y, e1.y);
      o1.z = pairpack(x1.z, e1.z); o1.w = pairpack(x1.w, e1.w);
      *(uint4*)&sA[cur ^ 1][wr0] = o0;
      *(uint4*)&sA[cur ^ 1][wr1] = o1;
    }
    __syncthreads();
  }

  const float inv = 0.70710678118654752f;
  float* dst = (seg == 0) ? out : pp;
#pragma unroll
  for (int nt = 0; nt < 4; ++nt) {
    const int col = bn0 + wn + nt * 16 + fr;  // m (output neuron)
    const float bias = (seg == 0 && j == 0) ? bl[col] : 0.0f;
#pragma unroll
    for (int mt = 0; mt < 4; ++mt) {
      const int row0 = bm0 + wm + mt * 16 + quad * 4;  // b
#pragma unroll
      for (int r = 0; r < 4; ++r)
        dst[((size_t)(row0 + r) * N_DIM + col) * 8 + j] =
            (acc[mt][nt][r] + bias) * inv;
    }
  }
}

// ------- addred: out += pp (f32, float4 grid-stride-free exact cover) ------

__global__ __launch_bounds__(256) void addred(float* __restrict__ out,
                                              const float* __restrict__ pp) {
  const size_t t = ((size_t)blockIdx.x * 256 + threadIdx.x) * 4;
  float4 a = *(float4*)(out + t);
  const float4 b = *(const float4*)(pp + t);
  a.x += b.x; a.y += b.y; a.z += b.z; a.w += b.w;
  *(float4*)(out + t) = a;
}

// ---------------- launch ----------------

extern "C" void kernel_launch(void* const* d_in, const int* in_sizes, int n_in,
                              void* d_out, int out_size, void* d_ws, size_t ws_size,
                              hipStream_t stream) {
  const float* x = (const float*)d_in[0];   // (2048,512,8)  f32
  const float* w = (const float*)d_in[1];   // (512,512,20)  f32
  const float* wr = (const float*)d_in[2];  // (512,512,4)   f32
  const float* wl = (const float*)d_in[3];  // (512,512,4)   f32
  const float* bl = (const float*)d_in[4];  // (512,)        f32
  const float* na = (const float*)d_in[5];  // (1,512,4)     f32
  float* out = (float*)d_out;               // (2048,512,8)  f32

  char* ws = (char*)d_ws;
  unsigned short* xt = (unsigned short*)(ws);                  // 16 MB
  unsigned short* xre = (unsigned short*)(ws + 16777216);      // 18 MB
  unsigned short* wrt = (unsigned short*)(ws + 35651584);      //  2 MB
  unsigned short* Wall = (unsigned short*)(ws + 37748736);     // 36 MB
  float* pp = (float*)(ws + 75497472);                         // 33.5 MB
  // total ws use: 109,051,904 B

  repack_x<<<4096, 256, 0, stream>>>(x, xt);
  repack_wr<<<1024, 256, 0, stream>>>(wr, wrt);
  build_W<<<1024, 256, 0, stream>>>(w, wl, Wall);
  gemm1<<<dim3(16, 4, 8), 256, 0, stream>>>(xt, wrt, xre);
  normk<<<4096, 256, 0, stream>>>(xre, na);
  gemm2<<<dim3(16, 8, 8), 256, 0, stream>>>(xt, xre, Wall, bl, out, pp);
  addred<<<8192, 256, 0, stream>>>(out, pp);
}

// Round 9
// 306.178 us; speedup vs baseline: 1.2141x; 1.2141x over previous
//
#include <hip/hip_runtime.h>
#include <stdint.h>

// FullyConnectedSteerableGeometricProductLayer (G(3,0), 8 blades)
// B=2048, N_IN=N_OUT=512, N_PATHS=20. ALL I/O IS FLOAT32; internal bf16 MFMA.
//
// R13 = R12 K-split, but BOTH segments write plane-separated f32 partials
// pp[seg][j][b][m] (full-line contiguous stores inside each block's private
// region -> zero cross-block line merging, no RMW at any occupancy).
// R12 post-mortem: 4 blocks/CU worked (Occ 33%) but interleaved out[b][m][8j]
// writes needed 8-j dirty-line merging; dirty WS ~8.4MB/XCD > 4MB L2 ->
// WRITE_SIZE 414MB RMW thrash. addred folds pp0+pp1 -> out (j-interleave),
// ~100MB, LLC-resident. Isolates the occupancy lever cleanly.

#define B_DIM 2048
#define N_DIM 512
#define PLANE (B_DIM * N_DIM)   // 1048576
#define WPLANE (N_DIM * N_DIM)  // 262144
#define KTOT (9 * N_DIM)        // 4608

using frag8 = __attribute__((ext_vector_type(8))) short;  // 8 bf16
using f32x4 = __attribute__((ext_vector_type(4))) float;  // MFMA acc

__device__ __forceinline__ float bf2f(unsigned short u) {
  union { unsigned int i; float f; } v;
  v.i = ((unsigned int)u) << 16;
  return v.f;
}
__device__ __forceinline__ unsigned short f2bf(float f) {  // RNE
  unsigned int u = __float_as_uint(f);
  return (unsigned short)((u + 0x7FFFu + ((u >> 16) & 1u)) >> 16);
}
// two bf16 pairs (dwords a,r) -> packed bf16 products (round-half-up)
__device__ __forceinline__ unsigned int pairpack(unsigned int a, unsigned int r) {
  const float pe = __uint_as_float(a << 16) * __uint_as_float(r << 16);
  const float po = __uint_as_float(a & 0xFFFF0000u) * __uint_as_float(r & 0xFFFF0000u);
  return __builtin_amdgcn_perm(__float_as_uint(po) + 0x8000u,
                               __float_as_uint(pe) + 0x8000u, 0x07060302u);
}

typedef const unsigned int __attribute__((address_space(1)))* gas_t;
typedef unsigned int __attribute__((address_space(3)))* las_t;
// async 16B/lane global->LDS; LDS dest = wave-uniform base + lane*16
__device__ __forceinline__ void gload16(const void* g, void* l) {
  __builtin_amdgcn_global_load_lds((gas_t)g, (las_t)l, 16, 0, 0);
}

// ---- Cayley tables (verified end-to-end R3/R4/R5): sgn(j,k), p(j,k), grade.
// i(j,k) = P(P(j)^P(k)) with P = swap(3,4) involution (R4/R5-verified).
#define SGN_INIT {                                                     \
  {0,0,0,0,0x8000,0x8000,0x8000,0x8000},                               \
  {0,0,0,0,0x8000,0x8000,0x8000,0x8000},                               \
  {0,0x8000,0,0,0,0,0x8000,0},                                         \
  {0,0x8000,0x8000,0,0x8000,0,0,0x8000},                               \
  {0,0x8000,0,0,0,0,0x8000,0},                                         \
  {0,0x8000,0x8000,0,0x8000,0,0,0x8000},                               \
  {0,0,0x8000,0,0,0x8000,0,0},                                         \
  {0,0,0x8000,0,0,0x8000,0,0} }
#define PJK_INIT {                                                     \
  {0,4,4,4,10,10,10,16},  {5,1,11,11,6,6,17,12},                       \
  {5,11,1,11,6,17,6,12},  {5,11,11,1,17,6,6,12},                       \
  {13,7,7,18,2,14,14,8},  {13,7,18,7,14,2,14,8},                       \
  {13,18,7,7,14,14,2,8},  {19,15,15,15,9,9,9,3} }
#define GR_INIT {0,1,1,1,2,2,2,3}

// ---------------- repack / prebuild (f32 in -> bf16 planes) ----------------

__global__ __launch_bounds__(256) void repack_x(const float* __restrict__ x,
                                                unsigned short* __restrict__ xt) {
  const int t = blockIdx.x * 256 + threadIdx.x;
  const float4 v0 = *(const float4*)(x + (size_t)t * 8);
  const float4 v1 = *(const float4*)(x + (size_t)t * 8 + 4);
  const float v[8] = {v0.x, v0.y, v0.z, v0.w, v1.x, v1.y, v1.z, v1.w};
#pragma unroll
  for (int i = 0; i < 8; ++i) xt[(size_t)i * PLANE + t] = f2bf(v[i]);
}

__global__ __launch_bounds__(256) void repack_wr(const float* __restrict__ wr,
                                                 unsigned short* __restrict__ wrt) {
  const int t = blockIdx.x * 256 + threadIdx.x;
  const float4 v = *(const float4*)(wr + (size_t)t * 4);
  const float p[4] = {v.x, v.y, v.z, v.w};
#pragma unroll
  for (int g = 0; g < 4; ++g) wrt[(size_t)g * WPLANE + t] = f2bf(p[g]);
}

__global__ __launch_bounds__(256) void build_W(const float* __restrict__ w,
                                               const float* __restrict__ wl,
                                               unsigned short* __restrict__ Wall) {
  constexpr int PJK[8][8] = PJK_INIT;
  constexpr unsigned short SGN[8][8] = SGN_INIT;
  constexpr int GR[8] = GR_INIT;
  const int t = blockIdx.x * 256 + threadIdx.x;
  const int m = t >> 9, n = t & 511;
  const float* wrow = w + (size_t)t * 20;
  const float* wlrow = wl + (size_t)t * 4;
  unsigned short w20[20];
#pragma unroll
  for (int p = 0; p < 20; ++p) w20[p] = f2bf(wrow[p]);
  unsigned short wl4[4];
#pragma unroll
  for (int g = 0; g < 4; ++g) wl4[g] = f2bf(wlrow[g]);
#pragma unroll
  for (int j = 0; j < 8; ++j) {
    const size_t base = ((size_t)j * N_DIM + m) * KTOT + n;
#pragma unroll
    for (int k = 0; k < 8; ++k)
      Wall[base + (size_t)k * N_DIM] = (unsigned short)(w20[PJK[j][k]] ^ SGN[j][k]);
    Wall[base + (size_t)8 * N_DIM] = wl4[GR[j]];
  }
}

__global__ __launch_bounds__(256) void normk(unsigned short* __restrict__ xre,
                                             const float* __restrict__ na) {
  const int t = blockIdx.x * 256 + threadIdx.x;
  const int n = t & 511;
  float v[8];
#pragma unroll
  for (int p = 0; p < 8; ++p) v[p] = bf2f(xre[(size_t)p * PLANE + t]);
  const float n0 = fabsf(v[0]);
  const float n1 = sqrtf(v[1] * v[1] + v[2] * v[2] + v[3] * v[3]);
  const float n2 = sqrtf(v[4] * v[4] + v[5] * v[5] + v[6] * v[6]);
  const float n3 = fabsf(v[7]);
  float f[4];
  const float nm[4] = {n0, n1, n2, n3};
#pragma unroll
  for (int g = 0; g < 4; ++g) {
    const float a = na[n * 4 + g];
    const float sig = 1.0f / (1.0f + __expf(-a));
    f[g] = sig * (nm[g] - 1.0f) + 1.0f + 1e-6f;
  }
  v[0] /= f[0];
  v[1] /= f[1]; v[2] /= f[1]; v[3] /= f[1];
  v[4] /= f[2]; v[5] /= f[2]; v[6] /= f[2];
  v[7] /= f[3];
#pragma unroll
  for (int p = 0; p < 8; ++p) xre[(size_t)p * PLANE + t] = f2bf(v[p]);
  xre[(size_t)8 * PLANE + t] = 0x3F80;  // 1.0 plane -> 'left' term in gemm2
}

// ------- gemm1: xre[z] = xt[z] * wrt[g(z)]^T  (128x128, 4 waves) -----------

__global__ __launch_bounds__(256, 3) void gemm1(const unsigned short* __restrict__ xt,
                                                const unsigned short* __restrict__ wrt,
                                                unsigned short* __restrict__ xre) {
  constexpr int GR[8] = GR_INIT;
  __shared__ __attribute__((aligned(16))) unsigned short sA[2][4096];
  __shared__ __attribute__((aligned(16))) unsigned short sB[2][4096];
  const int bm0 = blockIdx.x * 128, bn0 = blockIdx.y * 128, z = blockIdx.z;
  const unsigned short* A = xt + (size_t)z * PLANE;
  const unsigned short* Bm = wrt + (size_t)GR[z] * WPLANE;
  unsigned short* C = xre + (size_t)z * PLANE;

  const int tid = (int)threadIdx.x;
  const int l = tid & 63, w = tid >> 6;
  const int wm = (w >> 1) * 64, wn = (w & 1) * 64;
  const int fr = l & 15, quad = l >> 4, msw = (fr >> 1) & 3;
  const int rdA = (wm + fr) * 32 + (quad ^ msw) * 8;
  const int rdB = (wn + fr) * 32 + (quad ^ msw) * 8;
  const int ks = (((l & 3) ^ ((l >> 3) & 3))) * 8;
  const int r0 = w * 32 + (l >> 2);
  const unsigned short* pa0 = A + (size_t)(bm0 + r0) * N_DIM + ks;
  const unsigned short* pa1 = pa0 + (size_t)16 * N_DIM;
  const unsigned short* pb0 = Bm + (size_t)(bn0 + r0) * N_DIM + ks;
  const unsigned short* pb1 = pb0 + (size_t)16 * N_DIM;
  const int db = w * 1024;  // wave LDS dest base (ushorts); op1 = +512

  f32x4 acc[4][4];
#pragma unroll
  for (int mt = 0; mt < 4; ++mt)
#pragma unroll
    for (int nt = 0; nt < 4; ++nt) acc[mt][nt] = (f32x4){0.f, 0.f, 0.f, 0.f};

  gload16(pa0, &sA[0][db]);
  gload16(pa1, &sA[0][db + 512]);
  gload16(pb0, &sB[0][db]);
  gload16(pb1, &sB[0][db + 512]);
  __syncthreads();

#pragma unroll 2
  for (int it = 0; it < 16; ++it) {
    const int cur = it & 1;
    if (it < 15) {
      const int off = (it + 1) * 32;
      gload16(pa0 + off, &sA[cur ^ 1][db]);
      gload16(pa1 + off, &sA[cur ^ 1][db + 512]);
      gload16(pb0 + off, &sB[cur ^ 1][db]);
      gload16(pb1 + off, &sB[cur ^ 1][db + 512]);
    }
    frag8 af[4], bf[4];
#pragma unroll
    for (int t = 0; t < 4; ++t) af[t] = *(const frag8*)&sA[cur][rdA + t * 512];
#pragma unroll
    for (int t = 0; t < 4; ++t) bf[t] = *(const frag8*)&sB[cur][rdB + t * 512];
#pragma unroll
    for (int mt = 0; mt < 4; ++mt)
#pragma unroll
      for (int nt = 0; nt < 4; ++nt)
        acc[mt][nt] = __builtin_amdgcn_mfma_f32_16x16x32_bf16(af[mt], bf[nt], acc[mt][nt], 0, 0, 0);
    __syncthreads();
  }
  // C/D: col = lane&15, row = quad*4 + reg
#pragma unroll
  for (int mt = 0; mt < 4; ++mt) {
    const int row0 = bm0 + wm + mt * 16 + quad * 4;
#pragma unroll
    for (int nt = 0; nt < 4; ++nt) {
      const int col = bn0 + wn + nt * 16 + fr;
#pragma unroll
      for (int r = 0; r < 4; ++r)
        C[(size_t)(row0 + r) * N_DIM + col] = f2bf(acc[mt][nt][r]);
    }
  }
}

// ------- gemm2: pp[seg][j] = partial (pair * Wall_j)/sqrt(2), K-split ------
// grid (16, 8, 8): by = bn(2b) | seg(bit2). Both segs write private f32
// planes pp[(seg*8+j)][b][m] -> full-line contiguous stores, no RMW.
// 1024 independent blocks = 4/CU = 16 waves/CU.

__global__ __launch_bounds__(256, 4) void gemm2(const unsigned short* __restrict__ xt,
                                                const unsigned short* __restrict__ xre,
                                                const unsigned short* __restrict__ Wall,
                                                const float* __restrict__ bl,
                                                float* __restrict__ pp) {
  __shared__ __attribute__((aligned(16))) unsigned short sA[2][4096];
  __shared__ __attribute__((aligned(16))) unsigned short sB[2][4096];
  const int bm0 = blockIdx.x * 128;
  const int bn0 = ((int)blockIdx.y & 3) * 128;
  const int seg = (int)blockIdx.y >> 2;
  const int j = blockIdx.z;
  const int kc0 = seg * 72;  // first K32-chunk of this segment

  const int tid = (int)threadIdx.x;
  const int l = tid & 63, w = tid >> 6;
  const int wm = (w >> 1) * 64, wn = (w & 1) * 64;
  const int fr = l & 15, quad = l >> 4, msw = (fr >> 1) & 3;
  const int rdA = (wm + fr) * 32 + (quad ^ msw) * 8;
  const int rdB = (wn + fr) * 32 + (quad ^ msw) * 8;
  const int ks = (((l & 3) ^ ((l >> 3) & 3))) * 8;
  const int r0 = w * 32 + (l >> 2);
  const int db = w * 1024;
  const int pj = (j == 3 || j == 4) ? (j ^ 7) : j;  // P(j)

  // A sources: un-swizzled col (reg-staged); write slot swizzled.
  const size_t ar0 = (size_t)(bm0 + r0) * N_DIM + (l & 3) * 8;
  const size_t ar1 = ar0 + (size_t)16 * N_DIM;
  const int wr0 = r0 * 32 + ks, wr1 = wr0 + 512;  // (r0+16)*32+ks
  // B source: swizzled col, linear LDS dest via global_load_lds.
  const unsigned short* pw0 = Wall + ((size_t)j * N_DIM + bn0 + r0) * KTOT + ks;
  const unsigned short* pw1 = pw0 + (size_t)16 * KTOT;

  // plane index of xt for slice sl: ie = P(pj ^ P(sl)); sl=8 -> j
  auto ieof = [&](int sl) -> int {
    int ps = (sl == 3 || sl == 4) ? (sl ^ 7) : sl;
    int ix = pj ^ ps;
    ix = (ix == 3 || ix == 4) ? (ix ^ 7) : ix;
    return (sl == 8) ? j : ix;
  };

  f32x4 acc[4][4];
#pragma unroll
  for (int mt = 0; mt < 4; ++mt)
#pragma unroll
    for (int nt = 0; nt < 4; ++nt) acc[mt][nt] = (f32x4){0.f, 0.f, 0.f, 0.f};

  // ---- prologue: chunk kc0 staged (A packed+written, B gloads in flight)
  {
    const int sl0 = kc0 >> 4, n00 = (kc0 & 15) << 5;
    const unsigned short* bx = xt + (size_t)ieof(sl0) * PLANE;
    const unsigned short* be = xre + (size_t)sl0 * PLANE;
    const uint4 x0 = *(const uint4*)(bx + ar0 + n00);
    const uint4 e0 = *(const uint4*)(be + ar0 + n00);
    const uint4 x1 = *(const uint4*)(bx + ar1 + n00);
    const uint4 e1 = *(const uint4*)(be + ar1 + n00);
    gload16(pw0 + (size_t)kc0 * 32, &sB[0][db]);
    gload16(pw1 + (size_t)kc0 * 32, &sB[0][db + 512]);
    uint4 o0, o1;
    o0.x = pairpack(x0.x, e0.x); o0.y = pairpack(x0.y, e0.y);
    o0.z = pairpack(x0.z, e0.z); o0.w = pairpack(x0.w, e0.w);
    o1.x = pairpack(x1.x, e1.x); o1.y = pairpack(x1.y, e1.y);
    o1.z = pairpack(x1.z, e1.z); o1.w = pairpack(x1.w, e1.w);
    *(uint4*)&sA[0][wr0] = o0;
    *(uint4*)&sA[0][wr1] = o1;
  }
  __syncthreads();

#pragma unroll 2
  for (int it = 0; it < 72; ++it) {
    const int cur = it & 1;
    uint4 x0, e0, x1, e1;
    if (it < 71) {  // prefetch A regs + B gloads for chunk kc0+it+1
      const int kn = kc0 + it + 1;
      const int sl = kn >> 4, n0 = (kn & 15) << 5;
      int ps = (sl == 3 || sl == 4) ? (sl ^ 7) : sl;
      int ix = pj ^ ps;
      ix = (ix == 3 || ix == 4) ? (ix ^ 7) : ix;
      const int ie = (sl == 8) ? j : ix;
      const unsigned short* bx = xt + (size_t)ie * PLANE;
      const unsigned short* be = xre + (size_t)sl * PLANE;
      x0 = *(const uint4*)(bx + ar0 + n0);
      e0 = *(const uint4*)(be + ar0 + n0);
      x1 = *(const uint4*)(bx + ar1 + n0);
      e1 = *(const uint4*)(be + ar1 + n0);
      gload16(pw0 + (size_t)kn * 32, &sB[cur ^ 1][db]);
      gload16(pw1 + (size_t)kn * 32, &sB[cur ^ 1][db + 512]);
    }
    frag8 af[4], bf[4];
#pragma unroll
    for (int t = 0; t < 4; ++t) af[t] = *(const frag8*)&sA[cur][rdA + t * 512];
#pragma unroll
    for (int t = 0; t < 4; ++t) bf[t] = *(const frag8*)&sB[cur][rdB + t * 512];
#pragma unroll
    for (int mt = 0; mt < 4; ++mt)
#pragma unroll
      for (int nt = 0; nt < 4; ++nt)
        acc[mt][nt] = __builtin_amdgcn_mfma_f32_16x16x32_bf16(af[mt], bf[nt], acc[mt][nt], 0, 0, 0);
    if (it < 71) {  // pack + write A for next chunk (wait lands after MFMA)
      uint4 o0, o1;
      o0.x = pairpack(x0.x, e0.x); o0.y = pairpack(x0.y, e0.y);
      o0.z = pairpack(x0.z, e0.z); o0.w = pairpack(x0.w, e0.w);
      o1.x = pairpack(x1.x, e1.x); o1.y = pairpack(x1.y, e1.y);
      o1.z = pairpack(x1.z, e1.z); o1.w = pairpack(x1.w, e1.w);
      *(uint4*)&sA[cur ^ 1][wr0] = o0;
      *(uint4*)&sA[cur ^ 1][wr1] = o1;
    }
    __syncthreads();
  }

  const float inv = 0.70710678118654752f;
  float* dst = pp + (size_t)(seg * 8 + j) * PLANE;
#pragma unroll
  for (int nt = 0; nt < 4; ++nt) {
    const int col = bn0 + wn + nt * 16 + fr;  // m (output neuron)
    const float bias = (seg == 0 && j == 0) ? bl[col] : 0.0f;
#pragma unroll
    for (int mt = 0; mt < 4; ++mt) {
      const int row0 = bm0 + wm + mt * 16 + quad * 4;  // b
#pragma unroll
      for (int r = 0; r < 4; ++r)
        dst[(size_t)(row0 + r) * N_DIM + col] = (acc[mt][nt][r] + bias) * inv;
    }
  }
}

// ------- addred: out[b][m][j] = pp0[j][b][m] + pp1[j][b][m] ---------------

__global__ __launch_bounds__(256) void addred(const float* __restrict__ pp,
                                              float* __restrict__ out) {
  const size_t t = (size_t)blockIdx.x * 256 + threadIdx.x;  // (b,m) flat
  float v[8];
#pragma unroll
  for (int j = 0; j < 8; ++j)
    v[j] = pp[(size_t)j * PLANE + t] + pp[(size_t)(8 + j) * PLANE + t];
  const float4 lo = {v[0], v[1], v[2], v[3]};
  const float4 hi = {v[4], v[5], v[6], v[7]};
  *(float4*)(out + t * 8) = lo;
  *(float4*)(out + t * 8 + 4) = hi;
}

// ---------------- launch ----------------

extern "C" void kernel_launch(void* const* d_in, const int* in_sizes, int n_in,
                              void* d_out, int out_size, void* d_ws, size_t ws_size,
                              hipStream_t stream) {
  const float* x = (const float*)d_in[0];   // (2048,512,8)  f32
  const float* w = (const float*)d_in[1];   // (512,512,20)  f32
  const float* wr = (const float*)d_in[2];  // (512,512,4)   f32
  const float* wl = (const float*)d_in[3];  // (512,512,4)   f32
  const float* bl = (const float*)d_in[4];  // (512,)        f32
  const float* na = (const float*)d_in[5];  // (1,512,4)     f32
  float* out = (float*)d_out;               // (2048,512,8)  f32

  char* ws = (char*)d_ws;
  unsigned short* xt = (unsigned short*)(ws);                  // 16 MB
  unsigned short* xre = (unsigned short*)(ws + 16777216);      // 18 MB
  unsigned short* wrt = (unsigned short*)(ws + 35651584);      //  2 MB
  unsigned short* Wall = (unsigned short*)(ws + 37748736);     // 36 MB
  float* pp = (float*)(ws + 75497472);                         // 64 MB (2x8 planes)
  // total ws use: 142,606,336 B

  repack_x<<<4096, 256, 0, stream>>>(x, xt);
  repack_wr<<<1024, 256, 0, stream>>>(wr, wrt);
  build_W<<<1024, 256, 0, stream>>>(w, wl, Wall);
  gemm1<<<dim3(16, 4, 8), 256, 0, stream>>>(xt, wrt, xre);
  normk<<<4096, 256, 0, stream>>>(xre, na);
  gemm2<<<dim3(16, 8, 8), 256, 0, stream>>>(xt, xre, Wall, bl, pp);
  addred<<<4096, 256, 0, stream>>>(pp, out);
}